// Round 6
// baseline (611.616 us; speedup 1.0000x reference)
//
#include <hip/hip_runtime.h>
#include <cmath>

#define DMODEL 768
#define SEQ    1024
#define NH     12
#define HDIM   64
#define MTOT   16384   // 16 * 1024

typedef unsigned short ushort_t;
typedef __attribute__((ext_vector_type(8))) short short8v;
typedef __attribute__((ext_vector_type(4))) float f32x4;

union v8u { short8v v; unsigned u[4]; };

// round-to-nearest-even fp32 -> bf16 bits (scalar fallback, used in tiny kernels)
__device__ __forceinline__ ushort_t bf16rn(float x) {
  unsigned u = __float_as_uint(x);
  return (ushort_t)((u + 0x7FFFu + ((u >> 16) & 1u)) >> 16);
}
__device__ __forceinline__ void bsplit(float x, ushort_t& h, ushort_t& l) {
  h = bf16rn(x);
  float hf = __uint_as_float((unsigned)h << 16);
  l = bf16rn(x - hf);
}

// packed 2xf32 -> 2xbf16 (RNE): lo16 = bf16(a), hi16 = bf16(b)
__device__ __forceinline__ unsigned cvt_pk_bf16(float a, float b) {
  unsigned r;
  asm("v_cvt_pk_bf16_f32 %0, %1, %2" : "=v"(r) : "v"(a), "v"(b));
  return r;
}
// split two f32 into packed-bf16 hi-word and lo-word (element0 in lo16)
__device__ __forceinline__ void bsplit2(float x0, float x1, unsigned& hw, unsigned& lw) {
  hw = cvt_pk_bf16(x0, x1);
  const float h0 = __uint_as_float(hw << 16);
  const float h1 = __uint_as_float(hw & 0xFFFF0000u);
  lw = cvt_pk_bf16(x0 - h0, x1 - h1);
}

// async global -> LDS, 16 bytes per lane
__device__ __forceinline__ void gld16(const void* g, void* l) {
  __builtin_amdgcn_global_load_lds(
      (const __attribute__((address_space(1))) int*)g,
      (__attribute__((address_space(3))) int*)l, 16, 0, 0);
}

// ---------------------------------------------------------------------------
// RoPE tables (fp64-accurate): [cos_x | sin_x | cos_y | sin_y], each [1024][16]
// ---------------------------------------------------------------------------
__global__ __launch_bounds__(256)
void rope_table_kernel(float* __restrict__ tab) {
  int idx = blockIdx.x * 256 + threadIdx.x;
  if (idx >= SEQ * 16) return;
  int l = idx >> 4, p = idx & 15;
  double u = ((double)(l & 31) + 0.5) / 32.0;
  double v = ((double)(l >> 5) + 0.5) / 32.0;
  double freq = (double)p / (15.0 + 1e-9);
  double inv = pow(10000.0, -freq);
  tab[idx]         = (float)cos(u * inv);
  tab[16384 + idx] = (float)sin(u * inv);
  tab[32768 + idx] = (float)cos(v * inv);
  tab[49152 + idx] = (float)sin(v * inv);
}

// ---------------------------------------------------------------------------
// fp32 -> split bf16 hi/lo, 8 elems/thread
// ---------------------------------------------------------------------------
__global__ __launch_bounds__(256)
void split_x_kernel(const float* __restrict__ X, ushort_t* __restrict__ H,
                    ushort_t* __restrict__ L) {
  const int i = blockIdx.x * 256 + threadIdx.x;
  const float4 a = ((const float4*)X)[i * 2];
  const float4 b = ((const float4*)X)[i * 2 + 1];
  v8u h, l;
  bsplit2(a.x, a.y, h.u[0], l.u[0]);
  bsplit2(a.z, a.w, h.u[1], l.u[1]);
  bsplit2(b.x, b.y, h.u[2], l.u[2]);
  bsplit2(b.z, b.w, h.u[3], l.u[3]);
  ((short8v*)H)[i] = h.v;
  ((short8v*)L)[i] = l.v;
}

// ---------------------------------------------------------------------------
// W [768k][768n] fp32 -> Wt hi/lo bf16 [768n][768k] (transpose + split)
// ---------------------------------------------------------------------------
__global__ __launch_bounds__(256)
void wsplit_t_kernel(const float* __restrict__ W, ushort_t* __restrict__ TH,
                     ushort_t* __restrict__ TL) {
  __shared__ __align__(16) float T[64][65];
  const int t = threadIdx.x;
  const int kt = blockIdx.x, nt = blockIdx.y;
  const int r = t >> 2, c4 = (t & 3) * 16;
  const float* src = W + (size_t)(kt * 64 + r) * DMODEL + nt * 64 + c4;
#pragma unroll
  for (int i = 0; i < 16; i += 4)
    *(float4*)&T[r][c4 + i] = *(const float4*)&src[i];
  __syncthreads();
  short8v h0, h1, l0, l1;
#pragma unroll
  for (int i = 0; i < 8; ++i) {
    ushort_t hh, ll;
    bsplit(T[c4 + i][r], hh, ll);
    h0[i] = (short)hh; l0[i] = (short)ll;
  }
#pragma unroll
  for (int i = 0; i < 8; ++i) {
    ushort_t hh, ll;
    bsplit(T[c4 + 8 + i][r], hh, ll);
    h1[i] = (short)hh; l1[i] = (short)ll;
  }
  const size_t o = (size_t)(nt * 64 + r) * DMODEL + kt * 64 + c4;
  *(short8v*)&TH[o] = h0; *(short8v*)&TH[o + 8] = h1;
  *(short8v*)&TL[o] = l0; *(short8v*)&TL[o + 8] = l1;
}

// ---------------------------------------------------------------------------
// Split-bf16 MFMA GEMM: C[16384,768] = A @ B + bias (3-term hi/lo).
// mode 0: fp32 C [M][768]. mode 1: +RoPE +oscale, split, per-head [n][h][l][64].
// mode 2: split, per-head (no rope).
// ---------------------------------------------------------------------------
__global__ __launch_bounds__(256)
void gemm_mfma_kernel(const ushort_t* __restrict__ Ahi, const ushort_t* __restrict__ Alo,
                      const ushort_t* __restrict__ Bhi, const ushort_t* __restrict__ Blo,
                      const float* __restrict__ bias, float* __restrict__ Cout,
                      ushort_t* __restrict__ Ohi, ushort_t* __restrict__ Olo,
                      const float* __restrict__ rope, int mode, float oscale) {
  __shared__ __align__(16) ushort_t Ah[128][32];
  __shared__ __align__(16) ushort_t Al[128][32];
  __shared__ __align__(16) ushort_t Bh[128][32];
  __shared__ __align__(16) ushort_t Bl[128][32];

  const int t = threadIdx.x, lane = t & 63, w = t >> 6;
  const int l15 = lane & 15, l4 = lane >> 4;
  const int wm = w >> 1, wn = w & 1;
  const int m0 = blockIdx.x * 128, n0 = blockIdx.y * 128;

  const int crow = t >> 2, ccc = (t & 3) * 8;
  const ushort_t* pAh0 = Ahi + (size_t)(m0 + crow) * DMODEL + ccc;
  const ushort_t* pAh1 = pAh0 + (size_t)64 * DMODEL;
  const ushort_t* pAl0 = Alo + (size_t)(m0 + crow) * DMODEL + ccc;
  const ushort_t* pAl1 = pAl0 + (size_t)64 * DMODEL;
  const ushort_t* pBh0 = Bhi + (size_t)(n0 + crow) * DMODEL + ccc;
  const ushort_t* pBh1 = pBh0 + (size_t)64 * DMODEL;
  const ushort_t* pBl0 = Blo + (size_t)(n0 + crow) * DMODEL + ccc;
  const ushort_t* pBl1 = pBl0 + (size_t)64 * DMODEL;
  void* dAh0 = &Ah[crow][ccc];      void* dAh1 = &Ah[crow + 64][ccc];
  void* dAl0 = &Al[crow][ccc];      void* dAl1 = &Al[crow + 64][ccc];
  void* dBh0 = &Bh[crow][ccc];      void* dBh1 = &Bh[crow + 64][ccc];
  void* dBl0 = &Bl[crow][ccc];      void* dBl1 = &Bl[crow + 64][ccc];

  f32x4 acc[4][4] = {};

  for (int ks = 0; ks < DMODEL / 32; ++ks) {
    __syncthreads();
    gld16(pAh0, dAh0); gld16(pAh1, dAh1);
    gld16(pAl0, dAl0); gld16(pAl1, dAl1);
    gld16(pBh0, dBh0); gld16(pBh1, dBh1);
    gld16(pBl0, dBl0); gld16(pBl1, dBl1);
    pAh0 += 32; pAh1 += 32; pAl0 += 32; pAl1 += 32;
    pBh0 += 32; pBh1 += 32; pBl0 += 32; pBl1 += 32;
    __syncthreads();

    short8v afh[4], afl[4], bfh[4], bfl[4];
#pragma unroll
    for (int f = 0; f < 4; ++f) {
      afh[f] = *(const short8v*)&Ah[wm * 64 + f * 16 + l15][l4 * 8];
      afl[f] = *(const short8v*)&Al[wm * 64 + f * 16 + l15][l4 * 8];
      bfh[f] = *(const short8v*)&Bh[wn * 64 + f * 16 + l15][l4 * 8];
      bfl[f] = *(const short8v*)&Bl[wn * 64 + f * 16 + l15][l4 * 8];
    }
#pragma unroll
    for (int mf = 0; mf < 4; ++mf)
#pragma unroll
      for (int nf = 0; nf < 4; ++nf) {
        acc[mf][nf] = __builtin_amdgcn_mfma_f32_16x16x32_bf16(afh[mf], bfh[nf], acc[mf][nf], 0, 0, 0);
        acc[mf][nf] = __builtin_amdgcn_mfma_f32_16x16x32_bf16(afl[mf], bfh[nf], acc[mf][nf], 0, 0, 0);
        acc[mf][nf] = __builtin_amdgcn_mfma_f32_16x16x32_bf16(afh[mf], bfl[nf], acc[mf][nf], 0, 0, 0);
      }
  }

  float bcol[4];
#pragma unroll
  for (int nf = 0; nf < 4; ++nf) bcol[nf] = bias[n0 + wn * 64 + nf * 16 + l15];

  if (mode == 0) {
#pragma unroll
    for (int mf = 0; mf < 4; ++mf)
#pragma unroll
      for (int r = 0; r < 4; ++r) {
        const int m = m0 + wm * 64 + mf * 16 + l4 * 4 + r;
#pragma unroll
        for (int nf = 0; nf < 4; ++nf)
          Cout[(size_t)m * DMODEL + n0 + wn * 64 + nf * 16 + l15] = acc[mf][nf][r] + bcol[nf];
      }
  } else {
    const int h = blockIdx.y * 2 + wn;
#pragma unroll
    for (int mf = 0; mf < 4; ++mf)
#pragma unroll
      for (int r = 0; r < 4; ++r) {
        const int m = m0 + wm * 64 + mf * 16 + l4 * 4 + r;
        const int l = m & (SEQ - 1);
        const int nb = m >> 10;
        const size_t orow = ((size_t)(nb * NH + h) * SEQ + l) * HDIM;
        float vv[4];
#pragma unroll
        for (int nf = 0; nf < 4; ++nf) {
          float v = acc[mf][nf][r] + bcol[nf];
          if (mode == 1) {
            const float vp = __shfl_xor(v, 1, 64);
            const int tb = (nf < 2) ? 0 : 32768;
            const int pi = (nf & 1) * 8 + (l15 >> 1);
            const float c = rope[tb + l * 16 + pi];
            const float s = rope[tb + 16384 + l * 16 + pi];
            v = (l15 & 1) ? (vp * s + v * c) : (v * c - vp * s);
            v *= oscale;   // Q: log2e/8 (exp2-domain); K: 1.0
          }
          vv[nf] = v;
        }
        unsigned h01, l01, h23, l23;
        bsplit2(vv[0], vv[1], h01, l01);
        bsplit2(vv[2], vv[3], h23, l23);
        Ohi[orow + 0 * 16 + l15] = (ushort_t)(h01 & 0xFFFFu);
        Ohi[orow + 1 * 16 + l15] = (ushort_t)(h01 >> 16);
        Ohi[orow + 2 * 16 + l15] = (ushort_t)(h23 & 0xFFFFu);
        Ohi[orow + 3 * 16 + l15] = (ushort_t)(h23 >> 16);
        Olo[orow + 0 * 16 + l15] = (ushort_t)(l01 & 0xFFFFu);
        Olo[orow + 1 * 16 + l15] = (ushort_t)(l01 >> 16);
        Olo[orow + 2 * 16 + l15] = (ushort_t)(l23 & 0xFFFFu);
        Olo[orow + 3 * 16 + l15] = (ushort_t)(l23 >> 16);
      }
  }
}

// ---------------------------------------------------------------------------
// V transpose (bf16 hi/lo): [n][h][l][64] -> [n][h][d][1024]
// ---------------------------------------------------------------------------
__global__ __launch_bounds__(256)
void vtrans_kernel(const ushort_t* __restrict__ VH, const ushort_t* __restrict__ VL,
                   ushort_t* __restrict__ TH, ushort_t* __restrict__ TL) {
  __shared__ __align__(16) ushort_t Th[64][72];
  __shared__ __align__(16) ushort_t Tl[64][72];
  const int t = threadIdx.x;
  const int lt = blockIdx.x, h = blockIdx.y, n = blockIdx.z;
  const int r = t >> 2, c = (t & 3) * 16;
  const size_t src = ((size_t)(n * NH + h) * SEQ + lt * 64 + r) * HDIM + c;
  *(short8v*)&Th[r][c]     = *(const short8v*)&VH[src];
  *(short8v*)&Th[r][c + 8] = *(const short8v*)&VH[src + 8];
  *(short8v*)&Tl[r][c]     = *(const short8v*)&VL[src];
  *(short8v*)&Tl[r][c + 8] = *(const short8v*)&VL[src + 8];
  __syncthreads();
  short8v h0, h1, l0, l1;
#pragma unroll
  for (int i = 0; i < 8; ++i) { h0[i] = (short)Th[c + i][r];     l0[i] = (short)Tl[c + i][r]; }
#pragma unroll
  for (int i = 0; i < 8; ++i) { h1[i] = (short)Th[c + 8 + i][r]; l1[i] = (short)Tl[c + 8 + i][r]; }
  const size_t dst = ((size_t)(n * NH + h) * HDIM + r) * SEQ + lt * 64 + c;
  *(short8v*)&TH[dst]     = h0; *(short8v*)&TH[dst + 8] = h1;
  *(short8v*)&TL[dst]     = l0; *(short8v*)&TL[dst + 8] = l1;
}

// ---------------------------------------------------------------------------
// Flash attention, split-bf16 MFMA, exp2-domain softmax (Q pre-scaled by
// log2e/8). QBLK=128: 8 waves / 512 threads per block; K/V staged once per
// 128 q-rows. Separate K/V LDS, reg-prefetch, defer-max, deferred lrun
// reduce, cvt_pk-based P split.
// ---------------------------------------------------------------------------
__global__ __launch_bounds__(512)
void attn_mfma_kernel(const ushort_t* __restrict__ qh, const ushort_t* __restrict__ ql,
                      const ushort_t* __restrict__ kh, const ushort_t* __restrict__ kl,
                      const ushort_t* __restrict__ vth, const ushort_t* __restrict__ vtl,
                      ushort_t* __restrict__ abh, ushort_t* __restrict__ abl) {
  __shared__ __align__(16) ushort_t Kh[64][64];
  __shared__ __align__(16) ushort_t Kl[64][64];
  __shared__ __align__(16) ushort_t Vh[64][64];
  __shared__ __align__(16) ushort_t Vl[64][64];
  __shared__ __align__(16) float Ps[128][64];

  const int t = threadIdx.x;
  const int lane = t & 63, w = t >> 6;        // w in 0..7
  const int l15 = lane & 15, l4 = lane >> 4;

  const int bid = blockIdx.x;                 // 1536 blocks
  const int xcd = bid & 7, rest = bid >> 3;
  const int qt = rest & 7;                    // 8 q-tiles of 128 rows
  const int hl = (rest >> 3) * 8 + xcd;       // 0..191, head pinned to XCD
  const int h = hl % NH, n = hl / NH;

  const size_t base = (size_t)(n * NH + h) * (SEQ * HDIM);

  short8v qfh[2], qfl[2];
  {
    const size_t qoff = base + (size_t)(qt * 128 + w * 16 + l15) * HDIM + l4 * 8;
    qfh[0] = *(const short8v*)&qh[qoff];
    qfh[1] = *(const short8v*)&qh[qoff + 32];
    qfl[0] = *(const short8v*)&ql[qoff];
    qfl[1] = *(const short8v*)&ql[qoff + 32];
  }

  f32x4 Oa[4] = {};
  float mrun[4] = {-INFINITY, -INFINITY, -INFINITY, -INFINITY};
  float lp[4] = {0.f, 0.f, 0.f, 0.f};

  // staging: 512 lanes cover 64 rows x 64 ushorts per buffer, 1 chunk each
  const int sr = t >> 3, sc = t & 7;
  const int swc = (sc ^ (sr & 7)) * 8;

  short8v rkh, rkl, rvh, rvl;
  {
    const size_t gk = base + (size_t)sr * HDIM + sc * 8;
    rkh = *(const short8v*)&kh[gk];
    rkl = *(const short8v*)&kl[gk];
    const size_t gv = base + (size_t)sr * SEQ + sc * 8;
    rvh = *(const short8v*)&vth[gv];
    rvl = *(const short8v*)&vtl[gv];
  }

  for (int kt = 0; kt < 16; ++kt) {
    __syncthreads();
    *(short8v*)&Kh[sr][swc] = rkh;
    *(short8v*)&Kl[sr][swc] = rkl;
    *(short8v*)&Vh[sr][swc] = rvh;
    *(short8v*)&Vl[sr][swc] = rvl;
    __syncthreads();

    if (kt < 15) {
      const size_t gk = base + (size_t)((kt + 1) * 64 + sr) * HDIM + sc * 8;
      rkh = *(const short8v*)&kh[gk];
      rkl = *(const short8v*)&kl[gk];
      const size_t gv = base + (size_t)sr * SEQ + (kt + 1) * 64 + sc * 8;
      rvh = *(const short8v*)&vth[gv];
      rvl = *(const short8v*)&vtl[gv];
    }

    // S = Q K^T (3-term split); S is in log2 domain (Q pre-scaled by log2e/8)
    f32x4 S[4] = {};
    __builtin_amdgcn_s_setprio(1);
#pragma unroll
    for (int ks = 0; ks < 2; ++ks)
#pragma unroll
      for (int j = 0; j < 4; ++j) {
        const short8v bh = *(const short8v*)&Kh[l15 + 16 * j][((4 * ks + l4) ^ (l15 & 7)) * 8];
        const short8v bl = *(const short8v*)&Kl[l15 + 16 * j][((4 * ks + l4) ^ (l15 & 7)) * 8];
        S[j] = __builtin_amdgcn_mfma_f32_16x16x32_bf16(qfh[ks], bh, S[j], 0, 0, 0);
        S[j] = __builtin_amdgcn_mfma_f32_16x16x32_bf16(qfl[ks], bh, S[j], 0, 0, 0);
        S[j] = __builtin_amdgcn_mfma_f32_16x16x32_bf16(qfh[ks], bl, S[j], 0, 0, 0);
      }
    __builtin_amdgcn_s_setprio(0);

    // defer-max online softmax (log2 domain; 11.5 = 8*log2e)
    float m4[4];
    int ok = 1;
#pragma unroll
    for (int r = 0; r < 4; ++r) {
      m4[r] = fmaxf(fmaxf(S[0][r], S[1][r]), fmaxf(S[2][r], S[3][r]));
      ok &= (m4[r] <= mrun[r] + 11.5f) ? 1 : 0;
    }
    float p0[4], p1[4], p2[4], p3[4];
    if (__all(ok)) {
#pragma unroll
      for (int r = 0; r < 4; ++r) {
        p0[r] = __builtin_amdgcn_exp2f(S[0][r] - mrun[r]);
        p1[r] = __builtin_amdgcn_exp2f(S[1][r] - mrun[r]);
        p2[r] = __builtin_amdgcn_exp2f(S[2][r] - mrun[r]);
        p3[r] = __builtin_amdgcn_exp2f(S[3][r] - mrun[r]);
        lp[r] += (p0[r] + p1[r]) + (p2[r] + p3[r]);
      }
    } else {
#pragma unroll
      for (int r = 0; r < 4; ++r) {
        float tm = m4[r];
        tm = fmaxf(tm, __shfl_xor(tm, 1, 16));
        tm = fmaxf(tm, __shfl_xor(tm, 2, 16));
        tm = fmaxf(tm, __shfl_xor(tm, 4, 16));
        tm = fmaxf(tm, __shfl_xor(tm, 8, 16));
        const float nm  = fmaxf(mrun[r], tm);
        const float scl = __builtin_amdgcn_exp2f(mrun[r] - nm);
        mrun[r] = nm;
        p0[r] = __builtin_amdgcn_exp2f(S[0][r] - nm);
        p1[r] = __builtin_amdgcn_exp2f(S[1][r] - nm);
        p2[r] = __builtin_amdgcn_exp2f(S[2][r] - nm);
        p3[r] = __builtin_amdgcn_exp2f(S[3][r] - nm);
        lp[r] = lp[r] * scl + ((p0[r] + p1[r]) + (p2[r] + p3[r]));
        Oa[0][r] *= scl; Oa[1][r] *= scl; Oa[2][r] *= scl; Oa[3][r] *= scl;
      }
    }
#pragma unroll
    for (int r = 0; r < 4; ++r) {
      const int prow = w * 16 + l4 * 4 + r;
      const int sw = prow & 15;
      Ps[prow][(((l15)      >> 2) ^ sw) * 4 + (l15 & 3)] = p0[r];
      Ps[prow][(((l15 + 16) >> 2) ^ sw) * 4 + (l15 & 3)] = p1[r];
      Ps[prow][(((l15 + 32) >> 2) ^ sw) * 4 + (l15 & 3)] = p2[r];
      Ps[prow][(((l15 + 48) >> 2) ^ sw) * 4 + (l15 & 3)] = p3[r];
    }
    // Ps stripe is wave-local (rows w*16..w*16+15): no barrier needed

    // O += P V (3-term split), cvt_pk-based P split
#pragma unroll
    for (int ks = 0; ks < 2; ++ks) {
      float pf[8];
      *(f32x4*)&pf[0] = *(const f32x4*)&Ps[w * 16 + l15][((8 * ks + 2 * l4)     ^ l15) * 4];
      *(f32x4*)&pf[4] = *(const f32x4*)&Ps[w * 16 + l15][((8 * ks + 2 * l4 + 1) ^ l15) * 4];
      v8u ph, pl;
      bsplit2(pf[0], pf[1], ph.u[0], pl.u[0]);
      bsplit2(pf[2], pf[3], ph.u[1], pl.u[1]);
      bsplit2(pf[4], pf[5], ph.u[2], pl.u[2]);
      bsplit2(pf[6], pf[7], ph.u[3], pl.u[3]);
      __builtin_amdgcn_s_setprio(1);
#pragma unroll
      for (int j = 0; j < 4; ++j) {
        const short8v vh = *(const short8v*)&Vh[l15 + 16 * j][((4 * ks + l4) ^ (l15 & 7)) * 8];
        const short8v vl = *(const short8v*)&Vl[l15 + 16 * j][((4 * ks + l4) ^ (l15 & 7)) * 8];
        Oa[j] = __builtin_amdgcn_mfma_f32_16x16x32_bf16(ph.v, vh, Oa[j], 0, 0, 0);
        Oa[j] = __builtin_amdgcn_mfma_f32_16x16x32_bf16(pl.v, vh, Oa[j], 0, 0, 0);
        Oa[j] = __builtin_amdgcn_mfma_f32_16x16x32_bf16(ph.v, vl, Oa[j], 0, 0, 0);
      }
      __builtin_amdgcn_s_setprio(0);
    }
  }

  // epilogue: deferred cross-lane lrun reduction, normalize, bf16-split store
#pragma unroll
  for (int r = 0; r < 4; ++r) {
    float s = lp[r];
    s += __shfl_xor(s, 1, 16);
    s += __shfl_xor(s, 2, 16);
    s += __shfl_xor(s, 4, 16);
    s += __shfl_xor(s, 8, 16);
    const float inv = 1.0f / s;
    const int l = qt * 128 + w * 16 + l4 * 4 + r;
    const size_t row = ((size_t)n * SEQ + l) * DMODEL + h * HDIM;
    const float o0 = Oa[0][r] * inv, o1 = Oa[1][r] * inv;
    const float o2 = Oa[2][r] * inv, o3 = Oa[3][r] * inv;
    unsigned h01, l01, h23, l23;
    bsplit2(o0, o1, h01, l01);
    bsplit2(o2, o3, h23, l23);
    abh[row + 0 * 16 + l15] = (ushort_t)(h01 & 0xFFFFu);
    abh[row + 1 * 16 + l15] = (ushort_t)(h01 >> 16);
    abh[row + 2 * 16 + l15] = (ushort_t)(h23 & 0xFFFFu);
    abh[row + 3 * 16 + l15] = (ushort_t)(h23 >> 16);
    abl[row + 0 * 16 + l15] = (ushort_t)(l01 & 0xFFFFu);
    abl[row + 1 * 16 + l15] = (ushort_t)(l01 >> 16);
    abl[row + 2 * 16 + l15] = (ushort_t)(l23 & 0xFFFFu);
    abl[row + 3 * 16 + l15] = (ushort_t)(l23 >> 16);
  }
}

// ---------------------------------------------------------------------------
extern "C" void kernel_launch(void* const* d_in, const int* in_sizes, int n_in,
                              void* d_out, int out_size, void* d_ws, size_t ws_size,
                              hipStream_t stream) {
  (void)in_sizes; (void)n_in; (void)out_size;
  const float* Xq  = (const float*)d_in[0];
  const float* Xkv = (const float*)d_in[1];
  const float* Wq  = (const float*)d_in[2];
  const float* bq  = (const float*)d_in[3];
  const float* Wk  = (const float*)d_in[4];
  const float* bk  = (const float*)d_in[5];
  const float* Wv  = (const float*)d_in[6];
  const float* bv  = (const float*)d_in[7];
  const float* Wo  = (const float*)d_in[8];
  const float* bo  = (const float*)d_in[9];
  float* out = (float*)d_out;

  if (ws_size < 201588736ull) return;
  char* W = (char*)d_ws;
  const size_t HB = 25165824ull;
  float*    rope = (float*)W;
  ushort_t* xh  = (ushort_t*)(W + 262144);
  ushort_t* xl  = (ushort_t*)(W + 262144 + HB);
  ushort_t* vth = xh;
  ushort_t* vtl = xl;
  char* C0 = W + 262144 + 2 * HB;
  ushort_t* qhi = (ushort_t*)(C0);
  ushort_t* qlo = (ushort_t*)(C0 + HB);
  ushort_t* khi = (ushort_t*)(C0 + 2 * HB);
  ushort_t* klo = (ushort_t*)(C0 + 3 * HB);
  ushort_t* woth = (ushort_t*)(C0);
  ushort_t* wotl = woth + 589824;
  char* D0 = C0 + 4 * HB;
  ushort_t* vbh = (ushort_t*)(D0);
  ushort_t* vbl = (ushort_t*)(D0 + HB);
  ushort_t* abh = vbh;
  ushort_t* abl = vbl;
  ushort_t* wqth = (ushort_t*)d_out;            ushort_t* wqtl = wqth + 589824;
  ushort_t* wkth = wqth + 1179648;              ushort_t* wktl = wkth + 589824;
  ushort_t* wvth = wqth + 2359296;              ushort_t* wvtl = wvth + 589824;

  rope_table_kernel<<<64, 256, 0, stream>>>(rope);
  wsplit_t_kernel<<<dim3(12, 12), 256, 0, stream>>>(Wq, wqth, wqtl);
  wsplit_t_kernel<<<dim3(12, 12), 256, 0, stream>>>(Wk, wkth, wktl);
  wsplit_t_kernel<<<dim3(12, 12), 256, 0, stream>>>(Wv, wvth, wvtl);

  const dim3 gg(MTOT / 128, DMODEL / 128);
  const float q_scale = 0.125f * 1.44269504088896340736f;   // (1/8)*log2(e)

  split_x_kernel<<<6144, 256, 0, stream>>>(Xq, xh, xl);
  gemm_mfma_kernel<<<gg, 256, 0, stream>>>(xh, xl, wqth, wqtl, bq, nullptr, qhi, qlo, rope, 1, q_scale);

  split_x_kernel<<<6144, 256, 0, stream>>>(Xkv, xh, xl);
  gemm_mfma_kernel<<<gg, 256, 0, stream>>>(xh, xl, wkth, wktl, bk, nullptr, khi, klo, rope, 1, 1.0f);
  gemm_mfma_kernel<<<gg, 256, 0, stream>>>(xh, xl, wvth, wvtl, bv, nullptr, vbh, vbl, rope, 2, 1.0f);

  vtrans_kernel<<<dim3(16, NH, 16), 256, 0, stream>>>(vbh, vbl, vth, vtl);

  attn_mfma_kernel<<<1536, 512, 0, stream>>>(qhi, qlo, khi, klo, vth, vtl, abh, abl);

  wsplit_t_kernel<<<dim3(12, 12), 256, 0, stream>>>(Wo, woth, wotl);
  gemm_mfma_kernel<<<gg, 256, 0, stream>>>(abh, abl, woth, wotl, bo, out, nullptr, nullptr, rope, 0, 1.0f);
}

// Round 7
// 582.165 us; speedup vs baseline: 1.0506x; 1.0506x over previous
//
#include <hip/hip_runtime.h>
#include <cmath>

#define DMODEL 768
#define SEQ    1024
#define NH     12
#define HDIM   64
#define MTOT   16384   // 16 * 1024

typedef unsigned short ushort_t;
typedef __attribute__((ext_vector_type(8))) short short8v;
typedef __attribute__((ext_vector_type(4))) float f32x4;
typedef __attribute__((ext_vector_type(16))) float f32x16;

union v8u { short8v v; unsigned u[4]; };

// round-to-nearest-even fp32 -> bf16 bits (scalar, small kernels)
__device__ __forceinline__ ushort_t bf16rn(float x) {
  unsigned u = __float_as_uint(x);
  return (ushort_t)((u + 0x7FFFu + ((u >> 16) & 1u)) >> 16);
}
__device__ __forceinline__ void bsplit(float x, ushort_t& h, ushort_t& l) {
  h = bf16rn(x);
  float hf = __uint_as_float((unsigned)h << 16);
  l = bf16rn(x - hf);
}

// packed 2xf32 -> 2xbf16 (RNE): lo16 = bf16(a), hi16 = bf16(b)
__device__ __forceinline__ unsigned cvt_pk_bf16(float a, float b) {
  unsigned r;
  asm("v_cvt_pk_bf16_f32 %0, %1, %2" : "=v"(r) : "v"(a), "v"(b));
  return r;
}
// split two f32 into packed-bf16 hi-word and lo-word (element0 in lo16)
__device__ __forceinline__ void bsplit2(float x0, float x1, unsigned& hw, unsigned& lw) {
  hw = cvt_pk_bf16(x0, x1);
  const float h0 = __uint_as_float(hw << 16);
  const float h1 = __uint_as_float(hw & 0xFFFF0000u);
  lw = cvt_pk_bf16(x0 - h0, x1 - h1);
}

// async global -> LDS, 16 bytes per lane
__device__ __forceinline__ void gld16(const void* g, void* l) {
  __builtin_amdgcn_global_load_lds(
      (const __attribute__((address_space(1))) int*)g,
      (__attribute__((address_space(3))) int*)l, 16, 0, 0);
}

// ---------------------------------------------------------------------------
// RoPE tables (fp64-accurate): [cos_x | sin_x | cos_y | sin_y], each [1024][16]
// ---------------------------------------------------------------------------
__global__ __launch_bounds__(256)
void rope_table_kernel(float* __restrict__ tab) {
  int idx = blockIdx.x * 256 + threadIdx.x;
  if (idx >= SEQ * 16) return;
  int l = idx >> 4, p = idx & 15;
  double u = ((double)(l & 31) + 0.5) / 32.0;
  double v = ((double)(l >> 5) + 0.5) / 32.0;
  double freq = (double)p / (15.0 + 1e-9);
  double inv = pow(10000.0, -freq);
  tab[idx]         = (float)cos(u * inv);
  tab[16384 + idx] = (float)sin(u * inv);
  tab[32768 + idx] = (float)cos(v * inv);
  tab[49152 + idx] = (float)sin(v * inv);
}

// ---------------------------------------------------------------------------
// fp32 -> split bf16 hi/lo, 8 elems/thread
// ---------------------------------------------------------------------------
__global__ __launch_bounds__(256)
void split_x_kernel(const float* __restrict__ X, ushort_t* __restrict__ H,
                    ushort_t* __restrict__ L) {
  const int i = blockIdx.x * 256 + threadIdx.x;
  const float4 a = ((const float4*)X)[i * 2];
  const float4 b = ((const float4*)X)[i * 2 + 1];
  v8u h, l;
  bsplit2(a.x, a.y, h.u[0], l.u[0]);
  bsplit2(a.z, a.w, h.u[1], l.u[1]);
  bsplit2(b.x, b.y, h.u[2], l.u[2]);
  bsplit2(b.z, b.w, h.u[3], l.u[3]);
  ((short8v*)H)[i] = h.v;
  ((short8v*)L)[i] = l.v;
}

// ---------------------------------------------------------------------------
// W [768k][768n] fp32 -> Wt hi/lo bf16 [768n][768k] (transpose + split)
// ---------------------------------------------------------------------------
__global__ __launch_bounds__(256)
void wsplit_t_kernel(const float* __restrict__ W, ushort_t* __restrict__ TH,
                     ushort_t* __restrict__ TL) {
  __shared__ __align__(16) float T[64][65];
  const int t = threadIdx.x;
  const int kt = blockIdx.x, nt = blockIdx.y;
  const int r = t >> 2, c4 = (t & 3) * 16;
  const float* src = W + (size_t)(kt * 64 + r) * DMODEL + nt * 64 + c4;
#pragma unroll
  for (int i = 0; i < 16; i += 4)
    *(float4*)&T[r][c4 + i] = *(const float4*)&src[i];
  __syncthreads();
  short8v h0, h1, l0, l1;
#pragma unroll
  for (int i = 0; i < 8; ++i) {
    ushort_t hh, ll;
    bsplit(T[c4 + i][r], hh, ll);
    h0[i] = (short)hh; l0[i] = (short)ll;
  }
#pragma unroll
  for (int i = 0; i < 8; ++i) {
    ushort_t hh, ll;
    bsplit(T[c4 + 8 + i][r], hh, ll);
    h1[i] = (short)hh; l1[i] = (short)ll;
  }
  const size_t o = (size_t)(nt * 64 + r) * DMODEL + kt * 64 + c4;
  *(short8v*)&TH[o] = h0; *(short8v*)&TH[o + 8] = h1;
  *(short8v*)&TL[o] = l0; *(short8v*)&TL[o + 8] = l1;
}

// ---------------------------------------------------------------------------
// Split-bf16 MFMA GEMM: C[16384,768] = A @ B + bias (3-term hi/lo).
// mode 0: fp32 C [M][768]. mode 1: +RoPE +oscale, split, per-head [n][h][l][64].
// mode 2: split, per-head (no rope).
// ---------------------------------------------------------------------------
__global__ __launch_bounds__(256)
void gemm_mfma_kernel(const ushort_t* __restrict__ Ahi, const ushort_t* __restrict__ Alo,
                      const ushort_t* __restrict__ Bhi, const ushort_t* __restrict__ Blo,
                      const float* __restrict__ bias, float* __restrict__ Cout,
                      ushort_t* __restrict__ Ohi, ushort_t* __restrict__ Olo,
                      const float* __restrict__ rope, int mode, float oscale) {
  __shared__ __align__(16) ushort_t Ah[128][32];
  __shared__ __align__(16) ushort_t Al[128][32];
  __shared__ __align__(16) ushort_t Bh[128][32];
  __shared__ __align__(16) ushort_t Bl[128][32];

  const int t = threadIdx.x, lane = t & 63, w = t >> 6;
  const int l15 = lane & 15, l4 = lane >> 4;
  const int wm = w >> 1, wn = w & 1;
  const int m0 = blockIdx.x * 128, n0 = blockIdx.y * 128;

  const int crow = t >> 2, ccc = (t & 3) * 8;
  const ushort_t* pAh0 = Ahi + (size_t)(m0 + crow) * DMODEL + ccc;
  const ushort_t* pAh1 = pAh0 + (size_t)64 * DMODEL;
  const ushort_t* pAl0 = Alo + (size_t)(m0 + crow) * DMODEL + ccc;
  const ushort_t* pAl1 = pAl0 + (size_t)64 * DMODEL;
  const ushort_t* pBh0 = Bhi + (size_t)(n0 + crow) * DMODEL + ccc;
  const ushort_t* pBh1 = pBh0 + (size_t)64 * DMODEL;
  const ushort_t* pBl0 = Blo + (size_t)(n0 + crow) * DMODEL + ccc;
  const ushort_t* pBl1 = pBl0 + (size_t)64 * DMODEL;
  void* dAh0 = &Ah[crow][ccc];      void* dAh1 = &Ah[crow + 64][ccc];
  void* dAl0 = &Al[crow][ccc];      void* dAl1 = &Al[crow + 64][ccc];
  void* dBh0 = &Bh[crow][ccc];      void* dBh1 = &Bh[crow + 64][ccc];
  void* dBl0 = &Bl[crow][ccc];      void* dBl1 = &Bl[crow + 64][ccc];

  f32x4 acc[4][4] = {};

  for (int ks = 0; ks < DMODEL / 32; ++ks) {
    __syncthreads();
    gld16(pAh0, dAh0); gld16(pAh1, dAh1);
    gld16(pAl0, dAl0); gld16(pAl1, dAl1);
    gld16(pBh0, dBh0); gld16(pBh1, dBh1);
    gld16(pBl0, dBl0); gld16(pBl1, dBl1);
    pAh0 += 32; pAh1 += 32; pAl0 += 32; pAl1 += 32;
    pBh0 += 32; pBh1 += 32; pBl0 += 32; pBl1 += 32;
    __syncthreads();

    short8v afh[4], afl[4], bfh[4], bfl[4];
#pragma unroll
    for (int f = 0; f < 4; ++f) {
      afh[f] = *(const short8v*)&Ah[wm * 64 + f * 16 + l15][l4 * 8];
      afl[f] = *(const short8v*)&Al[wm * 64 + f * 16 + l15][l4 * 8];
      bfh[f] = *(const short8v*)&Bh[wn * 64 + f * 16 + l15][l4 * 8];
      bfl[f] = *(const short8v*)&Bl[wn * 64 + f * 16 + l15][l4 * 8];
    }
#pragma unroll
    for (int mf = 0; mf < 4; ++mf)
#pragma unroll
      for (int nf = 0; nf < 4; ++nf) {
        acc[mf][nf] = __builtin_amdgcn_mfma_f32_16x16x32_bf16(afh[mf], bfh[nf], acc[mf][nf], 0, 0, 0);
        acc[mf][nf] = __builtin_amdgcn_mfma_f32_16x16x32_bf16(afl[mf], bfh[nf], acc[mf][nf], 0, 0, 0);
        acc[mf][nf] = __builtin_amdgcn_mfma_f32_16x16x32_bf16(afh[mf], bfl[nf], acc[mf][nf], 0, 0, 0);
      }
  }

  float bcol[4];
#pragma unroll
  for (int nf = 0; nf < 4; ++nf) bcol[nf] = bias[n0 + wn * 64 + nf * 16 + l15];

  if (mode == 0) {
#pragma unroll
    for (int mf = 0; mf < 4; ++mf)
#pragma unroll
      for (int r = 0; r < 4; ++r) {
        const int m = m0 + wm * 64 + mf * 16 + l4 * 4 + r;
#pragma unroll
        for (int nf = 0; nf < 4; ++nf)
          Cout[(size_t)m * DMODEL + n0 + wn * 64 + nf * 16 + l15] = acc[mf][nf][r] + bcol[nf];
      }
  } else {
    const int h = blockIdx.y * 2 + wn;
#pragma unroll
    for (int mf = 0; mf < 4; ++mf)
#pragma unroll
      for (int r = 0; r < 4; ++r) {
        const int m = m0 + wm * 64 + mf * 16 + l4 * 4 + r;
        const int l = m & (SEQ - 1);
        const int nb = m >> 10;
        const size_t orow = ((size_t)(nb * NH + h) * SEQ + l) * HDIM;
        float vv[4];
#pragma unroll
        for (int nf = 0; nf < 4; ++nf) {
          float v = acc[mf][nf][r] + bcol[nf];
          if (mode == 1) {
            const float vp = __shfl_xor(v, 1, 64);
            const int tb = (nf < 2) ? 0 : 32768;
            const int pi = (nf & 1) * 8 + (l15 >> 1);
            const float c = rope[tb + l * 16 + pi];
            const float s = rope[tb + 16384 + l * 16 + pi];
            v = (l15 & 1) ? (vp * s + v * c) : (v * c - vp * s);
            v *= oscale;   // Q: log2e/8 (exp2-domain); K: 1.0
          }
          vv[nf] = v;
        }
        unsigned h01, l01, h23, l23;
        bsplit2(vv[0], vv[1], h01, l01);
        bsplit2(vv[2], vv[3], h23, l23);
        Ohi[orow + 0 * 16 + l15] = (ushort_t)(h01 & 0xFFFFu);
        Ohi[orow + 1 * 16 + l15] = (ushort_t)(h01 >> 16);
        Ohi[orow + 2 * 16 + l15] = (ushort_t)(h23 & 0xFFFFu);
        Ohi[orow + 3 * 16 + l15] = (ushort_t)(h23 >> 16);
        Olo[orow + 0 * 16 + l15] = (ushort_t)(l01 & 0xFFFFu);
        Olo[orow + 1 * 16 + l15] = (ushort_t)(l01 >> 16);
        Olo[orow + 2 * 16 + l15] = (ushort_t)(l23 & 0xFFFFu);
        Olo[orow + 3 * 16 + l15] = (ushort_t)(l23 >> 16);
      }
  }
}

// ---------------------------------------------------------------------------
// V transpose (bf16 hi/lo): [n][h][l][64] -> [n][h][d][1024]
// ---------------------------------------------------------------------------
__global__ __launch_bounds__(256)
void vtrans_kernel(const ushort_t* __restrict__ VH, const ushort_t* __restrict__ VL,
                   ushort_t* __restrict__ TH, ushort_t* __restrict__ TL) {
  __shared__ __align__(16) ushort_t Th[64][72];
  __shared__ __align__(16) ushort_t Tl[64][72];
  const int t = threadIdx.x;
  const int lt = blockIdx.x, h = blockIdx.y, n = blockIdx.z;
  const int r = t >> 2, c = (t & 3) * 16;
  const size_t src = ((size_t)(n * NH + h) * SEQ + lt * 64 + r) * HDIM + c;
  *(short8v*)&Th[r][c]     = *(const short8v*)&VH[src];
  *(short8v*)&Th[r][c + 8] = *(const short8v*)&VH[src + 8];
  *(short8v*)&Tl[r][c]     = *(const short8v*)&VL[src];
  *(short8v*)&Tl[r][c + 8] = *(const short8v*)&VL[src + 8];
  __syncthreads();
  short8v h0, h1, l0, l1;
#pragma unroll
  for (int i = 0; i < 8; ++i) { h0[i] = (short)Th[c + i][r];     l0[i] = (short)Tl[c + i][r]; }
#pragma unroll
  for (int i = 0; i < 8; ++i) { h1[i] = (short)Th[c + 8 + i][r]; l1[i] = (short)Tl[c + 8 + i][r]; }
  const size_t dst = ((size_t)(n * NH + h) * HDIM + r) * SEQ + lt * 64 + c;
  *(short8v*)&TH[dst]     = h0; *(short8v*)&TH[dst + 8] = h1;
  *(short8v*)&TL[dst]     = l0; *(short8v*)&TL[dst + 8] = l1;
}

// ---------------------------------------------------------------------------
// Flash attention v7: 32x32x16 MFMA, swapped QK^T (S^T per-lane rows),
// in-register P redistribution via shfl_xor(32) (no P LDS), double-buffered
// K/V staged with global_load_lds + pre-swizzled source, 1 barrier/kt.
// 4 waves x 32 q-rows = QBLK 128. Q pre-scaled by log2e/8 (exp2 domain).
// ---------------------------------------------------------------------------
__global__ __launch_bounds__(256)
void attn_mfma_kernel(const ushort_t* __restrict__ qh, const ushort_t* __restrict__ ql,
                      const ushort_t* __restrict__ kh, const ushort_t* __restrict__ kl,
                      const ushort_t* __restrict__ vth, const ushort_t* __restrict__ vtl,
                      ushort_t* __restrict__ abh, ushort_t* __restrict__ abl) {
  __shared__ __align__(16) ushort_t KHs[2][64][64];
  __shared__ __align__(16) ushort_t KLs[2][64][64];
  __shared__ __align__(16) ushort_t VHs[2][64][64];
  __shared__ __align__(16) ushort_t VLs[2][64][64];

  const int t = threadIdx.x;
  const int lane = t & 63, w = t >> 6;       // 4 waves
  const int l31 = lane & 31, l1 = lane >> 5;

  const int bid = blockIdx.x;                // 1536 blocks
  const int xcd = bid & 7, rest = bid >> 3;
  const int qt = rest & 7;                   // 8 q-tiles of 128 rows
  const int hl = (rest >> 3) * 8 + xcd;      // head pinned to XCD
  const int h = hl % NH, n = hl / NH;

  const size_t base = (size_t)(n * NH + h) * (SEQ * HDIM);

  // Q fragments: q-row = qt*128 + w*32 + l31; k = ks*16 + l1*8 + e
  short8v qfh[4], qfl[4];
  {
    const size_t qoff = base + (size_t)(qt * 128 + w * 32 + l31) * HDIM + l1 * 8;
#pragma unroll
    for (int ks = 0; ks < 4; ++ks) {
      qfh[ks] = *(const short8v*)&qh[qoff + ks * 16];
      qfl[ks] = *(const short8v*)&ql[qoff + ks * 16];
    }
  }

  // staging lane constants: pre-swizzled global source, linear LDS dest
  const int srow = lane >> 3;                // row within 8-row segment
  const int schk = (lane & 7) ^ srow;        // swizzled source chunk
  const int sA = 2 * w, sB = 2 * w + 1;      // this wave's two segments
  const size_t kofA = base + (size_t)(sA * 8 + srow) * HDIM + schk * 8;
  const size_t kofB = base + (size_t)(sB * 8 + srow) * HDIM + schk * 8;
  const size_t vofA = base + (size_t)(sA * 8 + srow) * SEQ + schk * 8;
  const size_t vofB = base + (size_t)(sB * 8 + srow) * SEQ + schk * 8;
  const int drA = sA * 8 + srow, drB = sB * 8 + srow, dc = (lane & 7) * 8;

  f32x16 Oa0 = {}, Oa1 = {};
  float mrun = -INFINITY, lp = 0.f;

#define ATTN_ISSUE(kt_, b_) do {                                            \
    const size_t ko_ = (size_t)(kt_) * (64 * HDIM);                         \
    const size_t vo_ = (size_t)(kt_) * 64;                                  \
    gld16(kh  + kofA + ko_, &KHs[b_][drA][dc]);                             \
    gld16(kh  + kofB + ko_, &KHs[b_][drB][dc]);                             \
    gld16(kl  + kofA + ko_, &KLs[b_][drA][dc]);                             \
    gld16(kl  + kofB + ko_, &KLs[b_][drB][dc]);                             \
    gld16(vth + vofA + vo_, &VHs[b_][drA][dc]);                             \
    gld16(vth + vofB + vo_, &VHs[b_][drB][dc]);                             \
    gld16(vtl + vofA + vo_, &VLs[b_][drA][dc]);                             \
    gld16(vtl + vofB + vo_, &VLs[b_][drB][dc]);                             \
  } while (0)

  ATTN_ISSUE(0, 0);

  for (int kt = 0; kt < 16; ++kt) {
    const int cur = kt & 1;
    __syncthreads();                 // drains vmcnt -> tile kt resident
    if (kt < 15) ATTN_ISSUE(kt + 1, cur ^ 1);   // flies under this kt's compute

    // ---- S^T = K · Q^T (A = K rows = keys, B = Q cols = q-rows), 3 terms
    f32x16 S0 = {}, S1 = {};
    __builtin_amdgcn_s_setprio(1);
#pragma unroll
    for (int ks = 0; ks < 4; ++ks) {
      const int cc = ((2 * ks + l1) ^ (l31 & 7)) * 8;
      const short8v k0h = *(const short8v*)&KHs[cur][l31][cc];
      const short8v k0l = *(const short8v*)&KLs[cur][l31][cc];
      const short8v k1h = *(const short8v*)&KHs[cur][32 + l31][cc];
      const short8v k1l = *(const short8v*)&KLs[cur][32 + l31][cc];
      S0 = __builtin_amdgcn_mfma_f32_32x32x16_bf16(k0h, qfh[ks], S0, 0, 0, 0);
      S1 = __builtin_amdgcn_mfma_f32_32x32x16_bf16(k1h, qfh[ks], S1, 0, 0, 0);
      S0 = __builtin_amdgcn_mfma_f32_32x32x16_bf16(k0l, qfh[ks], S0, 0, 0, 0);
      S1 = __builtin_amdgcn_mfma_f32_32x32x16_bf16(k1l, qfh[ks], S1, 0, 0, 0);
      S0 = __builtin_amdgcn_mfma_f32_32x32x16_bf16(k0h, qfl[ks], S0, 0, 0, 0);
      S1 = __builtin_amdgcn_mfma_f32_32x32x16_bf16(k1h, qfl[ks], S1, 0, 0, 0);
    }
    __builtin_amdgcn_s_setprio(0);

    // ---- defer-max online softmax (log2 domain), row q = l31 per lane
    float m01[16];
#pragma unroll
    for (int i = 0; i < 16; ++i) m01[i] = fmaxf(S0[i], S1[i]);
    float mx = fmaxf(fmaxf(fmaxf(m01[0], m01[1]), fmaxf(m01[2], m01[3])),
                     fmaxf(fmaxf(m01[4], m01[5]), fmaxf(m01[6], m01[7])));
    mx = fmaxf(mx, fmaxf(fmaxf(fmaxf(m01[8], m01[9]),  fmaxf(m01[10], m01[11])),
                         fmaxf(fmaxf(m01[12], m01[13]), fmaxf(m01[14], m01[15]))));
    if (__all(mx <= mrun + 11.5f)) {
#pragma unroll
      for (int i = 0; i < 16; ++i) {
        S0[i] = __builtin_amdgcn_exp2f(S0[i] - mrun);
        S1[i] = __builtin_amdgcn_exp2f(S1[i] - mrun);
      }
      f32x16 ts = S0 + S1;
      lp += ((((ts[0]+ts[1])+(ts[2]+ts[3]))+((ts[4]+ts[5])+(ts[6]+ts[7])))
           + (((ts[8]+ts[9])+(ts[10]+ts[11]))+((ts[12]+ts[13])+(ts[14]+ts[15]))));
    } else {
      const float om = fmaxf(mx, __shfl_xor(mx, 32));
      const float nm = fmaxf(mrun, om);
      const float scl = __builtin_amdgcn_exp2f(mrun - nm);
      mrun = nm;
#pragma unroll
      for (int i = 0; i < 16; ++i) {
        S0[i] = __builtin_amdgcn_exp2f(S0[i] - nm);
        S1[i] = __builtin_amdgcn_exp2f(S1[i] - nm);
      }
      f32x16 ts = S0 + S1;
      lp = lp * scl
         + ((((ts[0]+ts[1])+(ts[2]+ts[3]))+((ts[4]+ts[5])+(ts[6]+ts[7])))
          + (((ts[8]+ts[9])+(ts[10]+ts[11]))+((ts[12]+ts[13])+(ts[14]+ts[15]))));
      Oa0 = Oa0 * scl;
      Oa1 = Oa1 * scl;
    }

    // ---- O^T += V^T · P^T. P^T B-frag built in-register:
    // lane holds key quads {8c + 4*l1 + 0..3}, c = 4*half + m; partner (lane^32)
    // holds the other half of each chunk. B-frag for ks needs chunk c = 2ks+l1.
#pragma unroll
    for (int half = 0; half < 2; ++half) {
      unsigned uhx[4], uhy[4], ulx[4], uly[4];
      unsigned phx[4], phy[4], plx[4], ply[4];
#pragma unroll
      for (int m = 0; m < 4; ++m) {
        float p0, p1, p2, p3;
        if (half == 0) { p0 = S0[4*m]; p1 = S0[4*m+1]; p2 = S0[4*m+2]; p3 = S0[4*m+3]; }
        else           { p0 = S1[4*m]; p1 = S1[4*m+1]; p2 = S1[4*m+2]; p3 = S1[4*m+3]; }
        bsplit2(p0, p1, uhx[m], ulx[m]);
        bsplit2(p2, p3, uhy[m], uly[m]);
        phx[m] = (unsigned)__shfl_xor((int)uhx[m], 32);
        phy[m] = (unsigned)__shfl_xor((int)uhy[m], 32);
        plx[m] = (unsigned)__shfl_xor((int)ulx[m], 32);
        ply[m] = (unsigned)__shfl_xor((int)uly[m], 32);
      }
      __builtin_amdgcn_s_setprio(1);
#pragma unroll
      for (int kss = 0; kss < 2; ++kss) {
        v8u bfh, bfl;
        bfh.u[0] = l1 ? phx[2*kss+1] : uhx[2*kss];   // e0-1: from l1=0 lane
        bfh.u[1] = l1 ? phy[2*kss+1] : uhy[2*kss];   // e2-3
        bfh.u[2] = l1 ? uhx[2*kss+1] : phx[2*kss];   // e4-5: from l1=1 lane
        bfh.u[3] = l1 ? uhy[2*kss+1] : phy[2*kss];   // e6-7
        bfl.u[0] = l1 ? plx[2*kss+1] : ulx[2*kss];
        bfl.u[1] = l1 ? ply[2*kss+1] : uly[2*kss];
        bfl.u[2] = l1 ? ulx[2*kss+1] : plx[2*kss];
        bfl.u[3] = l1 ? uly[2*kss+1] : ply[2*kss];
        const int cc = ((4*half + 2*kss + l1) ^ (l31 & 7)) * 8;
        const short8v v0h = *(const short8v*)&VHs[cur][l31][cc];
        const short8v v0l = *(const short8v*)&VLs[cur][l31][cc];
        const short8v v1h = *(const short8v*)&VHs[cur][32 + l31][cc];
        const short8v v1l = *(const short8v*)&VLs[cur][32 + l31][cc];
        Oa0 = __builtin_amdgcn_mfma_f32_32x32x16_bf16(v0h, bfh.v, Oa0, 0, 0, 0);
        Oa1 = __builtin_amdgcn_mfma_f32_32x32x16_bf16(v1h, bfh.v, Oa1, 0, 0, 0);
        Oa0 = __builtin_amdgcn_mfma_f32_32x32x16_bf16(v0l, bfh.v, Oa0, 0, 0, 0);
        Oa1 = __builtin_amdgcn_mfma_f32_32x32x16_bf16(v1l, bfh.v, Oa1, 0, 0, 0);
        Oa0 = __builtin_amdgcn_mfma_f32_32x32x16_bf16(v0h, bfl.v, Oa0, 0, 0, 0);
        Oa1 = __builtin_amdgcn_mfma_f32_32x32x16_bf16(v1h, bfl.v, Oa1, 0, 0, 0);
      }
      __builtin_amdgcn_s_setprio(0);
    }
  }

  // ---- epilogue: combine partner lp, normalize, bf16-split store
  lp += __shfl_xor(lp, 32);
  const float inv = 1.0f / lp;
  const size_t orow = ((size_t)n * SEQ + qt * 128 + w * 32 + l31) * DMODEL + h * HDIM;
#pragma unroll
  for (int jd = 0; jd < 2; ++jd) {
#pragma unroll
    for (int g = 0; g < 4; ++g) {
      float o0, o1, o2, o3;
      if (jd == 0) { o0 = Oa0[4*g]; o1 = Oa0[4*g+1]; o2 = Oa0[4*g+2]; o3 = Oa0[4*g+3]; }
      else         { o0 = Oa1[4*g]; o1 = Oa1[4*g+1]; o2 = Oa1[4*g+2]; o3 = Oa1[4*g+3]; }
      o0 *= inv; o1 *= inv; o2 *= inv; o3 *= inv;
      unsigned h01, l01, h23, l23;
      bsplit2(o0, o1, h01, l01);
      bsplit2(o2, o3, h23, l23);
      const int d = 32 * jd + 8 * g + 4 * l1;   // row=(r&3)+8*(r>>2)+4*l1 (m101)
      uint2 sh; sh.x = h01; sh.y = h23;
      uint2 sl; sl.x = l01; sl.y = l23;
      *(uint2*)&abh[orow + d] = sh;
      *(uint2*)&abl[orow + d] = sl;
    }
  }
#undef ATTN_ISSUE
}

// ---------------------------------------------------------------------------
extern "C" void kernel_launch(void* const* d_in, const int* in_sizes, int n_in,
                              void* d_out, int out_size, void* d_ws, size_t ws_size,
                              hipStream_t stream) {
  (void)in_sizes; (void)n_in; (void)out_size;
  const float* Xq  = (const float*)d_in[0];
  const float* Xkv = (const float*)d_in[1];
  const float* Wq  = (const float*)d_in[2];
  const float* bq  = (const float*)d_in[3];
  const float* Wk  = (const float*)d_in[4];
  const float* bk  = (const float*)d_in[5];
  const float* Wv  = (const float*)d_in[6];
  const float* bv  = (const float*)d_in[7];
  const float* Wo  = (const float*)d_in[8];
  const float* bo  = (const float*)d_in[9];
  float* out = (float*)d_out;

  if (ws_size < 201588736ull) return;
  char* W = (char*)d_ws;
  const size_t HB = 25165824ull;
  float*    rope = (float*)W;
  ushort_t* xh  = (ushort_t*)(W + 262144);
  ushort_t* xl  = (ushort_t*)(W + 262144 + HB);
  ushort_t* vth = xh;
  ushort_t* vtl = xl;
  char* C0 = W + 262144 + 2 * HB;
  ushort_t* qhi = (ushort_t*)(C0);
  ushort_t* qlo = (ushort_t*)(C0 + HB);
  ushort_t* khi = (ushort_t*)(C0 + 2 * HB);
  ushort_t* klo = (ushort_t*)(C0 + 3 * HB);
  ushort_t* woth = (ushort_t*)(C0);
  ushort_t* wotl = woth + 589824;
  char* D0 = C0 + 4 * HB;
  ushort_t* vbh = (ushort_t*)(D0);
  ushort_t* vbl = (ushort_t*)(D0 + HB);
  ushort_t* abh = vbh;
  ushort_t* abl = vbl;
  ushort_t* wqth = (ushort_t*)d_out;            ushort_t* wqtl = wqth + 589824;
  ushort_t* wkth = wqth + 1179648;              ushort_t* wktl = wkth + 589824;
  ushort_t* wvth = wqth + 2359296;              ushort_t* wvtl = wvth + 589824;

  rope_table_kernel<<<64, 256, 0, stream>>>(rope);
  wsplit_t_kernel<<<dim3(12, 12), 256, 0, stream>>>(Wq, wqth, wqtl);
  wsplit_t_kernel<<<dim3(12, 12), 256, 0, stream>>>(Wk, wkth, wktl);
  wsplit_t_kernel<<<dim3(12, 12), 256, 0, stream>>>(Wv, wvth, wvtl);

  const dim3 gg(MTOT / 128, DMODEL / 128);
  const float q_scale = 0.125f * 1.44269504088896340736f;   // (1/8)*log2(e)

  split_x_kernel<<<6144, 256, 0, stream>>>(Xq, xh, xl);
  gemm_mfma_kernel<<<gg, 256, 0, stream>>>(xh, xl, wqth, wqtl, bq, nullptr, qhi, qlo, rope, 1, q_scale);

  split_x_kernel<<<6144, 256, 0, stream>>>(Xkv, xh, xl);
  gemm_mfma_kernel<<<gg, 256, 0, stream>>>(xh, xl, wkth, wktl, bk, nullptr, khi, klo, rope, 1, 1.0f);
  gemm_mfma_kernel<<<gg, 256, 0, stream>>>(xh, xl, wvth, wvtl, bv, nullptr, vbh, vbl, rope, 2, 1.0f);

  vtrans_kernel<<<dim3(16, NH, 16), 256, 0, stream>>>(vbh, vbl, vth, vtl);

  attn_mfma_kernel<<<1536, 256, 0, stream>>>(qhi, qlo, khi, klo, vth, vtl, abh, abl);

  wsplit_t_kernel<<<dim3(12, 12), 256, 0, stream>>>(Wo, woth, wotl);
  gemm_mfma_kernel<<<gg, 256, 0, stream>>>(abh, abl, woth, wotl, bo, out, nullptr, nullptr, rope, 0, 1.0f);
}

// Round 8
// 573.693 us; speedup vs baseline: 1.0661x; 1.0148x over previous
//
#include <hip/hip_runtime.h>
#include <cmath>

#define DMODEL 768
#define SEQ    1024
#define NH     12
#define HDIM   64
#define MTOT   16384   // 16 * 1024

typedef unsigned short ushort_t;
typedef __attribute__((ext_vector_type(8))) short short8v;
typedef __attribute__((ext_vector_type(4))) float f32x4;
typedef __attribute__((ext_vector_type(16))) float f32x16;
typedef __attribute__((ext_vector_type(2))) int i32x2v;

union v8u { short8v v; unsigned u[4]; };

// round-to-nearest-even fp32 -> bf16 bits (scalar, small kernels)
__device__ __forceinline__ ushort_t bf16rn(float x) {
  unsigned u = __float_as_uint(x);
  return (ushort_t)((u + 0x7FFFu + ((u >> 16) & 1u)) >> 16);
}
__device__ __forceinline__ void bsplit(float x, ushort_t& h, ushort_t& l) {
  h = bf16rn(x);
  float hf = __uint_as_float((unsigned)h << 16);
  l = bf16rn(x - hf);
}

// packed 2xf32 -> 2xbf16 (RNE): lo16 = bf16(a), hi16 = bf16(b)
__device__ __forceinline__ unsigned cvt_pk_bf16(float a, float b) {
  unsigned r;
  asm("v_cvt_pk_bf16_f32 %0, %1, %2" : "=v"(r) : "v"(a), "v"(b));
  return r;
}
// split two f32 into packed-bf16 hi-word and lo-word (element0 in lo16)
__device__ __forceinline__ void bsplit2(float x0, float x1, unsigned& hw, unsigned& lw) {
  hw = cvt_pk_bf16(x0, x1);
  const float h0 = __uint_as_float(hw << 16);
  const float h1 = __uint_as_float(hw & 0xFFFF0000u);
  lw = cvt_pk_bf16(x0 - h0, x1 - h1);
}

// v_permlane32_swap_b32: D.row1 (lanes>=32) <-> S.row0 (lanes<32).
// ret[0] = own a (lanes<32) | partner b (lanes>=32)
// ret[1] = partner a (lanes<32) | own b (lanes>=32)
__device__ __forceinline__ i32x2v pl32(unsigned a, unsigned b) {
  return __builtin_amdgcn_permlane32_swap((int)a, (int)b, false, false);
}

// async global -> LDS, 16 bytes per lane
__device__ __forceinline__ void gld16(const void* g, void* l) {
  __builtin_amdgcn_global_load_lds(
      (const __attribute__((address_space(1))) int*)g,
      (__attribute__((address_space(3))) int*)l, 16, 0, 0);
}

// ---------------------------------------------------------------------------
// RoPE tables (fp64-accurate): [cos_x | sin_x | cos_y | sin_y], each [1024][16]
// ---------------------------------------------------------------------------
__global__ __launch_bounds__(256)
void rope_table_kernel(float* __restrict__ tab) {
  int idx = blockIdx.x * 256 + threadIdx.x;
  if (idx >= SEQ * 16) return;
  int l = idx >> 4, p = idx & 15;
  double u = ((double)(l & 31) + 0.5) / 32.0;
  double v = ((double)(l >> 5) + 0.5) / 32.0;
  double freq = (double)p / (15.0 + 1e-9);
  double inv = pow(10000.0, -freq);
  tab[idx]         = (float)cos(u * inv);
  tab[16384 + idx] = (float)sin(u * inv);
  tab[32768 + idx] = (float)cos(v * inv);
  tab[49152 + idx] = (float)sin(v * inv);
}

// ---------------------------------------------------------------------------
// fp32 -> split bf16 hi/lo, 8 elems/thread
// ---------------------------------------------------------------------------
__global__ __launch_bounds__(256)
void split_x_kernel(const float* __restrict__ X, ushort_t* __restrict__ H,
                    ushort_t* __restrict__ L) {
  const int i = blockIdx.x * 256 + threadIdx.x;
  const float4 a = ((const float4*)X)[i * 2];
  const float4 b = ((const float4*)X)[i * 2 + 1];
  v8u h, l;
  bsplit2(a.x, a.y, h.u[0], l.u[0]);
  bsplit2(a.z, a.w, h.u[1], l.u[1]);
  bsplit2(b.x, b.y, h.u[2], l.u[2]);
  bsplit2(b.z, b.w, h.u[3], l.u[3]);
  ((short8v*)H)[i] = h.v;
  ((short8v*)L)[i] = l.v;
}

// ---------------------------------------------------------------------------
// W [768k][768n] fp32 -> Wt hi/lo bf16 [768n][768k] (transpose + split)
// ---------------------------------------------------------------------------
__global__ __launch_bounds__(256)
void wsplit_t_kernel(const float* __restrict__ W, ushort_t* __restrict__ TH,
                     ushort_t* __restrict__ TL) {
  __shared__ __align__(16) float T[64][65];
  const int t = threadIdx.x;
  const int kt = blockIdx.x, nt = blockIdx.y;
  const int r = t >> 2, c4 = (t & 3) * 16;
  const float* src = W + (size_t)(kt * 64 + r) * DMODEL + nt * 64 + c4;
#pragma unroll
  for (int i = 0; i < 16; i += 4)
    *(float4*)&T[r][c4 + i] = *(const float4*)&src[i];
  __syncthreads();
  short8v h0, h1, l0, l1;
#pragma unroll
  for (int i = 0; i < 8; ++i) {
    ushort_t hh, ll;
    bsplit(T[c4 + i][r], hh, ll);
    h0[i] = (short)hh; l0[i] = (short)ll;
  }
#pragma unroll
  for (int i = 0; i < 8; ++i) {
    ushort_t hh, ll;
    bsplit(T[c4 + 8 + i][r], hh, ll);
    h1[i] = (short)hh; l1[i] = (short)ll;
  }
  const size_t o = (size_t)(nt * 64 + r) * DMODEL + kt * 64 + c4;
  *(short8v*)&TH[o] = h0; *(short8v*)&TH[o + 8] = h1;
  *(short8v*)&TL[o] = l0; *(short8v*)&TL[o + 8] = l1;
}

// ---------------------------------------------------------------------------
// Split-bf16 MFMA GEMM: C[16384,768] = A @ B + bias (3-term hi/lo).
// mode 0: fp32 C [M][768]. mode 1: +RoPE +oscale, split, per-head [n][h][l][64].
// mode 2: split, per-head (no rope).
// ---------------------------------------------------------------------------
__global__ __launch_bounds__(256)
void gemm_mfma_kernel(const ushort_t* __restrict__ Ahi, const ushort_t* __restrict__ Alo,
                      const ushort_t* __restrict__ Bhi, const ushort_t* __restrict__ Blo,
                      const float* __restrict__ bias, float* __restrict__ Cout,
                      ushort_t* __restrict__ Ohi, ushort_t* __restrict__ Olo,
                      const float* __restrict__ rope, int mode, float oscale) {
  __shared__ __align__(16) ushort_t Ah[128][32];
  __shared__ __align__(16) ushort_t Al[128][32];
  __shared__ __align__(16) ushort_t Bh[128][32];
  __shared__ __align__(16) ushort_t Bl[128][32];

  const int t = threadIdx.x, lane = t & 63, w = t >> 6;
  const int l15 = lane & 15, l4 = lane >> 4;
  const int wm = w >> 1, wn = w & 1;
  const int m0 = blockIdx.x * 128, n0 = blockIdx.y * 128;

  const int crow = t >> 2, ccc = (t & 3) * 8;
  const ushort_t* pAh0 = Ahi + (size_t)(m0 + crow) * DMODEL + ccc;
  const ushort_t* pAh1 = pAh0 + (size_t)64 * DMODEL;
  const ushort_t* pAl0 = Alo + (size_t)(m0 + crow) * DMODEL + ccc;
  const ushort_t* pAl1 = pAl0 + (size_t)64 * DMODEL;
  const ushort_t* pBh0 = Bhi + (size_t)(n0 + crow) * DMODEL + ccc;
  const ushort_t* pBh1 = pBh0 + (size_t)64 * DMODEL;
  const ushort_t* pBl0 = Blo + (size_t)(n0 + crow) * DMODEL + ccc;
  const ushort_t* pBl1 = pBl0 + (size_t)64 * DMODEL;
  void* dAh0 = &Ah[crow][ccc];      void* dAh1 = &Ah[crow + 64][ccc];
  void* dAl0 = &Al[crow][ccc];      void* dAl1 = &Al[crow + 64][ccc];
  void* dBh0 = &Bh[crow][ccc];      void* dBh1 = &Bh[crow + 64][ccc];
  void* dBl0 = &Bl[crow][ccc];      void* dBl1 = &Bl[crow + 64][ccc];

  f32x4 acc[4][4] = {};

  for (int ks = 0; ks < DMODEL / 32; ++ks) {
    __syncthreads();
    gld16(pAh0, dAh0); gld16(pAh1, dAh1);
    gld16(pAl0, dAl0); gld16(pAl1, dAl1);
    gld16(pBh0, dBh0); gld16(pBh1, dBh1);
    gld16(pBl0, dBl0); gld16(pBl1, dBl1);
    pAh0 += 32; pAh1 += 32; pAl0 += 32; pAl1 += 32;
    pBh0 += 32; pBh1 += 32; pBl0 += 32; pBl1 += 32;
    __syncthreads();

    short8v afh[4], afl[4], bfh[4], bfl[4];
#pragma unroll
    for (int f = 0; f < 4; ++f) {
      afh[f] = *(const short8v*)&Ah[wm * 64 + f * 16 + l15][l4 * 8];
      afl[f] = *(const short8v*)&Al[wm * 64 + f * 16 + l15][l4 * 8];
      bfh[f] = *(const short8v*)&Bh[wn * 64 + f * 16 + l15][l4 * 8];
      bfl[f] = *(const short8v*)&Bl[wn * 64 + f * 16 + l15][l4 * 8];
    }
#pragma unroll
    for (int mf = 0; mf < 4; ++mf)
#pragma unroll
      for (int nf = 0; nf < 4; ++nf) {
        acc[mf][nf] = __builtin_amdgcn_mfma_f32_16x16x32_bf16(afh[mf], bfh[nf], acc[mf][nf], 0, 0, 0);
        acc[mf][nf] = __builtin_amdgcn_mfma_f32_16x16x32_bf16(afl[mf], bfh[nf], acc[mf][nf], 0, 0, 0);
        acc[mf][nf] = __builtin_amdgcn_mfma_f32_16x16x32_bf16(afh[mf], bfl[nf], acc[mf][nf], 0, 0, 0);
      }
  }

  float bcol[4];
#pragma unroll
  for (int nf = 0; nf < 4; ++nf) bcol[nf] = bias[n0 + wn * 64 + nf * 16 + l15];

  if (mode == 0) {
#pragma unroll
    for (int mf = 0; mf < 4; ++mf)
#pragma unroll
      for (int r = 0; r < 4; ++r) {
        const int m = m0 + wm * 64 + mf * 16 + l4 * 4 + r;
#pragma unroll
        for (int nf = 0; nf < 4; ++nf)
          Cout[(size_t)m * DMODEL + n0 + wn * 64 + nf * 16 + l15] = acc[mf][nf][r] + bcol[nf];
      }
  } else {
    const int h = blockIdx.y * 2 + wn;
#pragma unroll
    for (int mf = 0; mf < 4; ++mf)
#pragma unroll
      for (int r = 0; r < 4; ++r) {
        const int m = m0 + wm * 64 + mf * 16 + l4 * 4 + r;
        const int l = m & (SEQ - 1);
        const int nb = m >> 10;
        const size_t orow = ((size_t)(nb * NH + h) * SEQ + l) * HDIM;
        float vv[4];
#pragma unroll
        for (int nf = 0; nf < 4; ++nf) {
          float v = acc[mf][nf][r] + bcol[nf];
          if (mode == 1) {
            const float vp = __shfl_xor(v, 1, 64);
            const int tb = (nf < 2) ? 0 : 32768;
            const int pi = (nf & 1) * 8 + (l15 >> 1);
            const float c = rope[tb + l * 16 + pi];
            const float s = rope[tb + 16384 + l * 16 + pi];
            v = (l15 & 1) ? (vp * s + v * c) : (v * c - vp * s);
            v *= oscale;   // Q: log2e/8 (exp2-domain); K: 1.0
          }
          vv[nf] = v;
        }
        unsigned h01, l01, h23, l23;
        bsplit2(vv[0], vv[1], h01, l01);
        bsplit2(vv[2], vv[3], h23, l23);
        Ohi[orow + 0 * 16 + l15] = (ushort_t)(h01 & 0xFFFFu);
        Ohi[orow + 1 * 16 + l15] = (ushort_t)(h01 >> 16);
        Ohi[orow + 2 * 16 + l15] = (ushort_t)(h23 & 0xFFFFu);
        Ohi[orow + 3 * 16 + l15] = (ushort_t)(h23 >> 16);
        Olo[orow + 0 * 16 + l15] = (ushort_t)(l01 & 0xFFFFu);
        Olo[orow + 1 * 16 + l15] = (ushort_t)(l01 >> 16);
        Olo[orow + 2 * 16 + l15] = (ushort_t)(l23 & 0xFFFFu);
        Olo[orow + 3 * 16 + l15] = (ushort_t)(l23 >> 16);
      }
  }
}

// ---------------------------------------------------------------------------
// V transpose (bf16 hi/lo): [n][h][l][64] -> [n][h][d][1024]
// ---------------------------------------------------------------------------
__global__ __launch_bounds__(256)
void vtrans_kernel(const ushort_t* __restrict__ VH, const ushort_t* __restrict__ VL,
                   ushort_t* __restrict__ TH, ushort_t* __restrict__ TL) {
  __shared__ __align__(16) ushort_t Th[64][72];
  __shared__ __align__(16) ushort_t Tl[64][72];
  const int t = threadIdx.x;
  const int lt = blockIdx.x, h = blockIdx.y, n = blockIdx.z;
  const int r = t >> 2, c = (t & 3) * 16;
  const size_t src = ((size_t)(n * NH + h) * SEQ + lt * 64 + r) * HDIM + c;
  *(short8v*)&Th[r][c]     = *(const short8v*)&VH[src];
  *(short8v*)&Th[r][c + 8] = *(const short8v*)&VH[src + 8];
  *(short8v*)&Tl[r][c]     = *(const short8v*)&VL[src];
  *(short8v*)&Tl[r][c + 8] = *(const short8v*)&VL[src + 8];
  __syncthreads();
  short8v h0, h1, l0, l1;
#pragma unroll
  for (int i = 0; i < 8; ++i) { h0[i] = (short)Th[c + i][r];     l0[i] = (short)Tl[c + i][r]; }
#pragma unroll
  for (int i = 0; i < 8; ++i) { h1[i] = (short)Th[c + 8 + i][r]; l1[i] = (short)Tl[c + 8 + i][r]; }
  const size_t dst = ((size_t)(n * NH + h) * HDIM + r) * SEQ + lt * 64 + c;
  *(short8v*)&TH[dst]     = h0; *(short8v*)&TH[dst + 8] = h1;
  *(short8v*)&TL[dst]     = l0; *(short8v*)&TL[dst + 8] = l1;
}

// ---------------------------------------------------------------------------
// Flash attention v8: 32x32x16 MFMA, swapped QK^T (S^T per-lane rows),
// in-register P redistribution via permlane32_swap (VALU, no LDS traffic),
// double-buffered K/V staged with global_load_lds + pre-swizzled source,
// 1 barrier/kt. 4 waves x 32 q-rows = QBLK 128. Q pre-scaled by log2e/8.
// ---------------------------------------------------------------------------
__global__ __launch_bounds__(256)
void attn_mfma_kernel(const ushort_t* __restrict__ qh, const ushort_t* __restrict__ ql,
                      const ushort_t* __restrict__ kh, const ushort_t* __restrict__ kl,
                      const ushort_t* __restrict__ vth, const ushort_t* __restrict__ vtl,
                      ushort_t* __restrict__ abh, ushort_t* __restrict__ abl) {
  __shared__ __align__(16) ushort_t KHs[2][64][64];
  __shared__ __align__(16) ushort_t KLs[2][64][64];
  __shared__ __align__(16) ushort_t VHs[2][64][64];
  __shared__ __align__(16) ushort_t VLs[2][64][64];

  const int t = threadIdx.x;
  const int lane = t & 63, w = t >> 6;       // 4 waves
  const int l31 = lane & 31, l1 = lane >> 5;

  const int bid = blockIdx.x;                // 1536 blocks
  const int xcd = bid & 7, rest = bid >> 3;
  const int qt = rest & 7;                   // 8 q-tiles of 128 rows
  const int hl = (rest >> 3) * 8 + xcd;      // head pinned to XCD
  const int h = hl % NH, n = hl / NH;

  const size_t base = (size_t)(n * NH + h) * (SEQ * HDIM);

  // Q fragments: q-row = qt*128 + w*32 + l31; k = ks*16 + l1*8 + e
  short8v qfh[4], qfl[4];
  {
    const size_t qoff = base + (size_t)(qt * 128 + w * 32 + l31) * HDIM + l1 * 8;
#pragma unroll
    for (int ks = 0; ks < 4; ++ks) {
      qfh[ks] = *(const short8v*)&qh[qoff + ks * 16];
      qfl[ks] = *(const short8v*)&ql[qoff + ks * 16];
    }
  }

  // staging lane constants: pre-swizzled global source, linear LDS dest
  const int srow = lane >> 3;                // row within 8-row segment
  const int schk = (lane & 7) ^ srow;        // swizzled source chunk
  const int sA = 2 * w, sB = 2 * w + 1;      // this wave's two segments
  const size_t kofA = base + (size_t)(sA * 8 + srow) * HDIM + schk * 8;
  const size_t kofB = base + (size_t)(sB * 8 + srow) * HDIM + schk * 8;
  const size_t vofA = base + (size_t)(sA * 8 + srow) * SEQ + schk * 8;
  const size_t vofB = base + (size_t)(sB * 8 + srow) * SEQ + schk * 8;
  const int drA = sA * 8 + srow, drB = sB * 8 + srow, dc = (lane & 7) * 8;

  f32x16 Oa0 = {}, Oa1 = {};
  float mrun = -INFINITY, lp = 0.f;

#define ATTN_ISSUE(kt_, b_) do {                                            \
    const size_t ko_ = (size_t)(kt_) * (64 * HDIM);                         \
    const size_t vo_ = (size_t)(kt_) * 64;                                  \
    gld16(kh  + kofA + ko_, &KHs[b_][drA][dc]);                             \
    gld16(kh  + kofB + ko_, &KHs[b_][drB][dc]);                             \
    gld16(kl  + kofA + ko_, &KLs[b_][drA][dc]);                             \
    gld16(kl  + kofB + ko_, &KLs[b_][drB][dc]);                             \
    gld16(vth + vofA + vo_, &VHs[b_][drA][dc]);                             \
    gld16(vth + vofB + vo_, &VHs[b_][drB][dc]);                             \
    gld16(vtl + vofA + vo_, &VLs[b_][drA][dc]);                             \
    gld16(vtl + vofB + vo_, &VLs[b_][drB][dc]);                             \
  } while (0)

  ATTN_ISSUE(0, 0);

  for (int kt = 0; kt < 16; ++kt) {
    const int cur = kt & 1;
    __syncthreads();                 // drains vmcnt -> tile kt resident
    if (kt < 15) ATTN_ISSUE(kt + 1, cur ^ 1);   // flies under this kt's compute

    // ---- S^T = K · Q^T (A = K rows = keys, B = Q cols = q-rows), 3 terms
    f32x16 S0 = {}, S1 = {};
    __builtin_amdgcn_s_setprio(1);
#pragma unroll
    for (int ks = 0; ks < 4; ++ks) {
      const int cc = ((2 * ks + l1) ^ (l31 & 7)) * 8;
      const short8v k0h = *(const short8v*)&KHs[cur][l31][cc];
      const short8v k0l = *(const short8v*)&KLs[cur][l31][cc];
      const short8v k1h = *(const short8v*)&KHs[cur][32 + l31][cc];
      const short8v k1l = *(const short8v*)&KLs[cur][32 + l31][cc];
      S0 = __builtin_amdgcn_mfma_f32_32x32x16_bf16(k0h, qfh[ks], S0, 0, 0, 0);
      S1 = __builtin_amdgcn_mfma_f32_32x32x16_bf16(k1h, qfh[ks], S1, 0, 0, 0);
      S0 = __builtin_amdgcn_mfma_f32_32x32x16_bf16(k0l, qfh[ks], S0, 0, 0, 0);
      S1 = __builtin_amdgcn_mfma_f32_32x32x16_bf16(k1l, qfh[ks], S1, 0, 0, 0);
      S0 = __builtin_amdgcn_mfma_f32_32x32x16_bf16(k0h, qfl[ks], S0, 0, 0, 0);
      S1 = __builtin_amdgcn_mfma_f32_32x32x16_bf16(k1h, qfl[ks], S1, 0, 0, 0);
    }
    __builtin_amdgcn_s_setprio(0);

    // ---- defer-max online softmax (log2 domain), row q = l31 per lane
    float m01[16];
#pragma unroll
    for (int i = 0; i < 16; ++i) m01[i] = fmaxf(S0[i], S1[i]);
    float mx = fmaxf(fmaxf(fmaxf(m01[0], m01[1]), fmaxf(m01[2], m01[3])),
                     fmaxf(fmaxf(m01[4], m01[5]), fmaxf(m01[6], m01[7])));
    mx = fmaxf(mx, fmaxf(fmaxf(fmaxf(m01[8], m01[9]),  fmaxf(m01[10], m01[11])),
                         fmaxf(fmaxf(m01[12], m01[13]), fmaxf(m01[14], m01[15]))));
    if (__all(mx <= mrun + 11.5f)) {
#pragma unroll
      for (int i = 0; i < 16; ++i) {
        S0[i] = __builtin_amdgcn_exp2f(S0[i] - mrun);
        S1[i] = __builtin_amdgcn_exp2f(S1[i] - mrun);
      }
      f32x16 ts = S0 + S1;
      lp += ((((ts[0]+ts[1])+(ts[2]+ts[3]))+((ts[4]+ts[5])+(ts[6]+ts[7])))
           + (((ts[8]+ts[9])+(ts[10]+ts[11]))+((ts[12]+ts[13])+(ts[14]+ts[15]))));
    } else {
      const float om = fmaxf(mx, __shfl_xor(mx, 32));
      const float nm = fmaxf(mrun, om);
      const float scl = __builtin_amdgcn_exp2f(mrun - nm);
      mrun = nm;
#pragma unroll
      for (int i = 0; i < 16; ++i) {
        S0[i] = __builtin_amdgcn_exp2f(S0[i] - nm);
        S1[i] = __builtin_amdgcn_exp2f(S1[i] - nm);
      }
      f32x16 ts = S0 + S1;
      lp = lp * scl
         + ((((ts[0]+ts[1])+(ts[2]+ts[3]))+((ts[4]+ts[5])+(ts[6]+ts[7])))
          + (((ts[8]+ts[9])+(ts[10]+ts[11]))+((ts[12]+ts[13])+(ts[14]+ts[15]))));
      Oa0 = Oa0 * scl;
      Oa1 = Oa1 * scl;
    }

    // ---- O^T += V^T · P^T. P^T B-frag built in-register:
    // lane holds key quads {8c + 4*l1 + 0..3}, c = 4*half + m; partner (lane^32)
    // holds the other half of each chunk. B-frag for kss needs chunk c = 2kss+l1.
    // permlane32_swap(x[2kss], x[2kss+1]) -> ret0 = own x0 | partner x1 (= u[0]),
    // ret1 = partner x0 | own x1 (= u[2]). No selects needed.
#pragma unroll
    for (int half = 0; half < 2; ++half) {
      unsigned hx[4], hy[4], lx[4], ly[4];
#pragma unroll
      for (int m = 0; m < 4; ++m) {
        float p0, p1, p2, p3;
        if (half == 0) { p0 = S0[4*m]; p1 = S0[4*m+1]; p2 = S0[4*m+2]; p3 = S0[4*m+3]; }
        else           { p0 = S1[4*m]; p1 = S1[4*m+1]; p2 = S1[4*m+2]; p3 = S1[4*m+3]; }
        bsplit2(p0, p1, hx[m], lx[m]);
        bsplit2(p2, p3, hy[m], ly[m]);
      }
      __builtin_amdgcn_s_setprio(1);
#pragma unroll
      for (int kss = 0; kss < 2; ++kss) {
        const i32x2v rhx = pl32(hx[2*kss], hx[2*kss+1]);
        const i32x2v rhy = pl32(hy[2*kss], hy[2*kss+1]);
        const i32x2v rlx = pl32(lx[2*kss], lx[2*kss+1]);
        const i32x2v rly = pl32(ly[2*kss], ly[2*kss+1]);
        v8u bfh, bfl;
        bfh.u[0] = (unsigned)rhx[0]; bfh.u[1] = (unsigned)rhy[0];
        bfh.u[2] = (unsigned)rhx[1]; bfh.u[3] = (unsigned)rhy[1];
        bfl.u[0] = (unsigned)rlx[0]; bfl.u[1] = (unsigned)rly[0];
        bfl.u[2] = (unsigned)rlx[1]; bfl.u[3] = (unsigned)rly[1];
        const int cc = ((4*half + 2*kss + l1) ^ (l31 & 7)) * 8;
        const short8v v0h = *(const short8v*)&VHs[cur][l31][cc];
        const short8v v0l = *(const short8v*)&VLs[cur][l31][cc];
        const short8v v1h = *(const short8v*)&VHs[cur][32 + l31][cc];
        const short8v v1l = *(const short8v*)&VLs[cur][32 + l31][cc];
        Oa0 = __builtin_amdgcn_mfma_f32_32x32x16_bf16(v0h, bfh.v, Oa0, 0, 0, 0);
        Oa1 = __builtin_amdgcn_mfma_f32_32x32x16_bf16(v1h, bfh.v, Oa1, 0, 0, 0);
        Oa0 = __builtin_amdgcn_mfma_f32_32x32x16_bf16(v0l, bfh.v, Oa0, 0, 0, 0);
        Oa1 = __builtin_amdgcn_mfma_f32_32x32x16_bf16(v1l, bfh.v, Oa1, 0, 0, 0);
        Oa0 = __builtin_amdgcn_mfma_f32_32x32x16_bf16(v0h, bfl.v, Oa0, 0, 0, 0);
        Oa1 = __builtin_amdgcn_mfma_f32_32x32x16_bf16(v1h, bfl.v, Oa1, 0, 0, 0);
      }
      __builtin_amdgcn_s_setprio(0);
    }
  }

  // ---- epilogue: combine partner lp, normalize, bf16-split store
  lp += __shfl_xor(lp, 32);
  const float inv = 1.0f / lp;
  const size_t orow = ((size_t)n * SEQ + qt * 128 + w * 32 + l31) * DMODEL + h * HDIM;
#pragma unroll
  for (int jd = 0; jd < 2; ++jd) {
#pragma unroll
    for (int g = 0; g < 4; ++g) {
      float o0, o1, o2, o3;
      if (jd == 0) { o0 = Oa0[4*g]; o1 = Oa0[4*g+1]; o2 = Oa0[4*g+2]; o3 = Oa0[4*g+3]; }
      else         { o0 = Oa1[4*g]; o1 = Oa1[4*g+1]; o2 = Oa1[4*g+2]; o3 = Oa1[4*g+3]; }
      o0 *= inv; o1 *= inv; o2 *= inv; o3 *= inv;
      unsigned h01, l01, h23, l23;
      bsplit2(o0, o1, h01, l01);
      bsplit2(o2, o3, h23, l23);
      const int d = 32 * jd + 8 * g + 4 * l1;   // row=(r&3)+8*(r>>2)+4*l1 (m101)
      uint2 sh; sh.x = h01; sh.y = h23;
      uint2 sl; sl.x = l01; sl.y = l23;
      *(uint2*)&abh[orow + d] = sh;
      *(uint2*)&abl[orow + d] = sl;
    }
  }
#undef ATTN_ISSUE
}

// ---------------------------------------------------------------------------
extern "C" void kernel_launch(void* const* d_in, const int* in_sizes, int n_in,
                              void* d_out, int out_size, void* d_ws, size_t ws_size,
                              hipStream_t stream) {
  (void)in_sizes; (void)n_in; (void)out_size;
  const float* Xq  = (const float*)d_in[0];
  const float* Xkv = (const float*)d_in[1];
  const float* Wq  = (const float*)d_in[2];
  const float* bq  = (const float*)d_in[3];
  const float* Wk  = (const float*)d_in[4];
  const float* bk  = (const float*)d_in[5];
  const float* Wv  = (const float*)d_in[6];
  const float* bv  = (const float*)d_in[7];
  const float* Wo  = (const float*)d_in[8];
  const float* bo  = (const float*)d_in[9];
  float* out = (float*)d_out;

  if (ws_size < 201588736ull) return;
  char* W = (char*)d_ws;
  const size_t HB = 25165824ull;
  float*    rope = (float*)W;
  ushort_t* xh  = (ushort_t*)(W + 262144);
  ushort_t* xl  = (ushort_t*)(W + 262144 + HB);
  ushort_t* vth = xh;
  ushort_t* vtl = xl;
  char* C0 = W + 262144 + 2 * HB;
  ushort_t* qhi = (ushort_t*)(C0);
  ushort_t* qlo = (ushort_t*)(C0 + HB);
  ushort_t* khi = (ushort_t*)(C0 + 2 * HB);
  ushort_t* klo = (ushort_t*)(C0 + 3 * HB);
  ushort_t* woth = (ushort_t*)(C0);
  ushort_t* wotl = woth + 589824;
  char* D0 = C0 + 4 * HB;
  ushort_t* vbh = (ushort_t*)(D0);
  ushort_t* vbl = (ushort_t*)(D0 + HB);
  ushort_t* abh = vbh;
  ushort_t* abl = vbl;
  ushort_t* wqth = (ushort_t*)d_out;            ushort_t* wqtl = wqth + 589824;
  ushort_t* wkth = wqth + 1179648;              ushort_t* wktl = wkth + 589824;
  ushort_t* wvth = wqth + 2359296;              ushort_t* wvtl = wvth + 589824;

  rope_table_kernel<<<64, 256, 0, stream>>>(rope);
  wsplit_t_kernel<<<dim3(12, 12), 256, 0, stream>>>(Wq, wqth, wqtl);
  wsplit_t_kernel<<<dim3(12, 12), 256, 0, stream>>>(Wk, wkth, wktl);
  wsplit_t_kernel<<<dim3(12, 12), 256, 0, stream>>>(Wv, wvth, wvtl);

  const dim3 gg(MTOT / 128, DMODEL / 128);
  const float q_scale = 0.125f * 1.44269504088896340736f;   // (1/8)*log2(e)

  split_x_kernel<<<6144, 256, 0, stream>>>(Xq, xh, xl);
  gemm_mfma_kernel<<<gg, 256, 0, stream>>>(xh, xl, wqth, wqtl, bq, nullptr, qhi, qlo, rope, 1, q_scale);

  split_x_kernel<<<6144, 256, 0, stream>>>(Xkv, xh, xl);
  gemm_mfma_kernel<<<gg, 256, 0, stream>>>(xh, xl, wkth, wktl, bk, nullptr, khi, klo, rope, 1, 1.0f);
  gemm_mfma_kernel<<<gg, 256, 0, stream>>>(xh, xl, wvth, wvtl, bv, nullptr, vbh, vbl, rope, 2, 1.0f);

  vtrans_kernel<<<dim3(16, NH, 16), 256, 0, stream>>>(vbh, vbl, vth, vtl);

  attn_mfma_kernel<<<1536, 256, 0, stream>>>(qhi, qlo, khi, klo, vth, vtl, abh, abl);

  wsplit_t_kernel<<<dim3(12, 12), 256, 0, stream>>>(Wo, woth, wotl);
  gemm_mfma_kernel<<<gg, 256, 0, stream>>>(abh, abl, woth, wotl, bo, out, nullptr, nullptr, rope, 0, 1.0f);
}